// Round 4
// baseline (626.460 us; speedup 1.0000x reference)
//
#include <hip/hip_runtime.h>
#include <cfloat>
#include <cstdint>

// Problem constants
#define NROWS 131072
#define DIMD  128
#define KCODE 1024
// 1-pass bf16 score error bound B ~= 0.12 (6-sigma MFMA err 0.10 + index-packing quant 0.02).
// pair band > 2B, tri band > 2B: outside tri-band argmin is provably in {i1,i2}.
#define BANDPAIR 0.28f
#define BANDTRI  0.32f

typedef __attribute__((ext_vector_type(8))) short short8;  // 8 bf16 = 4 VGPRs
typedef __attribute__((ext_vector_type(4))) float f32x4;

union U4S8 { uint4 u; short8 s; };

// ---- workspace layout (bytes); total ~3.95 MB ----
#define WS_RF_CNT    0          // int   (full-refine count)
#define WS_RC_CNT    4          // int   (recheck count)
#define WS_LOSSADJ   8          // double
#define WS_COUNTS    16         // int[1024]
#define WS_SUMS      4608       // float[K*D] = 512 KB ([k][d])
#define WS_ZERO_BYTES 528896    // memset [0, WS_ZERO_BYTES)
#define WS_OFFSETS   528896     // int[1024]
#define WS_CURSOR    532992     // int[1024]
#define WS_E2        537088     // float[1024]
#define WS_ET        541184     // float[K*D] (ET[k][d])
#define WS_BHI       1065472    // uint4[16384] = 256 KB (B hi fragments)
#define WS_IDX       1327616    // int[N]
#define WS_ROWLIST   1851904    // int[N]
#define WS_RF_ROWS   2376192    // int[N]
#define WS_RC_ROWS   2900480    // int[N]
#define WS_RC_PAIR   3424768    // int[N]  ((i1<<10)|i2)
#define WS_PARTIALS  3949056    // float[512] per-block loss partials
// end: 3951104

// ---- output offsets (in floats), reference return order ----
#define OUT_QST  ((size_t)0)
#define OUT_EMB  ((size_t)NROWS * DIMD)
#define OUT_CNT  (OUT_EMB + (size_t)DIMD * KCODE)
#define OUT_ES   (OUT_CNT + KCODE)
#define OUT_LOSS (OUT_ES + (size_t)DIMD * KCODE)

// bf16 round-to-nearest-even of a float, as uint16 payload
__device__ __forceinline__ unsigned bf16rne(float f) {
    union { float f; unsigned u; } c; c.f = f;
    return (c.u + 0x7fffu + ((c.u >> 16) & 1u)) >> 16;
}

// ============================================================
// Fused prep: B hi-fragments in MFMA order + e2[k] = sum_d E[d][k]^2.
// Fragment fi = (NB*4 + t)*64 + lane; lane holds B[k = t*32 + (lane>>4)*8 + j]
// [n = NB*16 + (lane&15)], j = 0..7 (k is the d-dimension).
__global__ void vq_prep(const float* __restrict__ E, float* __restrict__ e2,
                        uint4* __restrict__ Bhi) {
    int gid = blockIdx.x * 256 + threadIdx.x;   // 0..16383 == fi
    int l = gid & 63;
    int t = (gid >> 6) & 3;
    int NB = gid >> 8;
    int n = NB * 16 + (l & 15);
    int k0 = t * 32 + (l >> 4) * 8;
    unsigned hu[8];
    #pragma unroll
    for (int j = 0; j < 8; ++j)
        hu[j] = bf16rne(E[(size_t)(k0 + j) * KCODE + n]);
    Bhi[gid] = make_uint4(hu[0] | (hu[1] << 16), hu[2] | (hu[3] << 16),
                          hu[4] | (hu[5] << 16), hu[6] | (hu[7] << 16));
    if (gid < KCODE) {
        float s = 0.f;
        for (int d = 0; d < DIMD; ++d) {
            float v = E[(size_t)d * KCODE + gid];
            s = fmaf(v, v, s);
        }
        e2[gid] = s;
    }
}

// ET[k][d] = E[d][k]  (LDS-tiled transpose)
__global__ void vq_transpose(const float* __restrict__ E, float* __restrict__ ET) {
    __shared__ float tile[32][33];
    int kb = blockIdx.x * 32, db = blockIdx.y * 32;
    int tx = threadIdx.x, ty = threadIdx.y;  // 32 x 8
    #pragma unroll
    for (int j = 0; j < 32; j += 8)
        tile[ty + j][tx] = E[(size_t)(db + ty + j) * KCODE + kb + tx];
    __syncthreads();
    #pragma unroll
    for (int j = 0; j < 32; j += 8)
        ET[(size_t)(kb + ty + j) * DIMD + db + tx] = tile[tx][ty + j];
}

// ============================================================
__device__ __forceinline__ void async16(const uint4* g, uint4* l) {
    __builtin_amdgcn_global_load_lds(
        (const __attribute__((address_space(1))) void*)g,
        (__attribute__((address_space(3))) void*)l, 16, 0, 0);
}

// Main kernel: 1-pass bf16 MFMA scores s = e2[k] - 2 x.e_k, per-row top-3
// tracking with col index packed in low 10 mantissa bits (med3 branchless).
// 256 rows/block, 4 waves x 64 rows. B hi chunks (64 codes = 16 KB) double-
// buffered via global_load_lds. Fused epilogue: histogram, recheck/refine
// lists, q_st write + commitment-loss partial.
__global__ __launch_bounds__(256, 3) void vq_argmin(
        const float* __restrict__ x, const uint4* __restrict__ Bhi,
        const float* __restrict__ e2, const float* __restrict__ ET,
        int* __restrict__ idx, int* __restrict__ counts,
        int* __restrict__ rc_rows, int* __restrict__ rc_pair, int* __restrict__ rc_cnt,
        int* __restrict__ rf_rows, int* __restrict__ rf_cnt,
        float* __restrict__ out, float* __restrict__ partials) {

    __shared__ uint4 Bs[2][1024];   // 2 x 16 KB (prologue: 4x8KB wave scratch)

    const int tid = threadIdx.x;
    const int w = tid >> 6, l = tid & 63;
    const int m = l & 15, q = l >> 4;
    const int row0 = blockIdx.x * 256;
    const int rw = row0 + w * 64;

    // ---------- A-phase: build hi A-fragments in registers ----------
    short8 ah[4][4];                                 // [m-tile][k-tile]
    float4* sc4 = ((float4*)&Bs[0][0]) + w * 512;    // 8 KB scratch per wave

    #pragma unroll
    for (int mt = 0; mt < 4; ++mt) {
        int rm = rw + mt * 16;
        #pragma unroll
        for (int i = 0; i < 8; ++i) {
            int f = i * 64 + l, r = f >> 5, g = f & 31;
            float4 v = ((const float4*)x)[(size_t)(rm + r) * 32 + g];
            sc4[r * 32 + (g ^ ((r & 7) << 2))] = v;
        }
        __builtin_amdgcn_s_waitcnt(0);
        int sw = (m & 7) << 2;
        #pragma unroll
        for (int t = 0; t < 4; ++t) {
            int g0 = t * 8 + q * 2;
            float4 va = sc4[m * 32 + (g0 ^ sw)];
            float4 vb = sc4[m * 32 + ((g0 + 1) ^ sw)];
            float f8[8] = {va.x, va.y, va.z, va.w, vb.x, vb.y, vb.z, vb.w};
            unsigned hu[8];
            #pragma unroll
            for (int j = 0; j < 8; ++j) hu[j] = bf16rne(f8[j]);
            U4S8 ch;
            ch.u = make_uint4(hu[0] | (hu[1] << 16), hu[2] | (hu[3] << 16),
                              hu[4] | (hu[5] << 16), hu[6] | (hu[7] << 16));
            ah[mt][t] = ch.s;
        }
    }

    float m1q[16], m2q[16], m3[16];   // slot = mt*4 + r
    #pragma unroll
    for (int k = 0; k < 16; ++k) { m1q[k] = 1e30f; m2q[k] = 1e30f; m3[k] = 1e30f; }

    __syncthreads();   // scratch reads done before staging overwrites

    // stage chunk 0 (16 KB, wave-partitioned; LDS dst = uniform base + lane*16)
    {
        const uint4* src = Bhi + w * 256 + l;
        uint4* dst = &Bs[0][0] + w * 256;
        #pragma unroll
        for (int j = 0; j < 4; ++j) async16(src + j * 64, dst + j * 64 + l);
    }
    __syncthreads();

    for (int c = 0; c < 16; ++c) {
        if (c < 15) {
            const uint4* src = Bhi + (c + 1) * 1024 + w * 256 + l;
            uint4* dst = &Bs[(c + 1) & 1][0] + w * 256;
            #pragma unroll
            for (int j = 0; j < 4; ++j) async16(src + j * 64, dst + j * 64 + l);
        }
        const uint4* buf = &Bs[c & 1][0];
        #pragma unroll
        for (int b = 0; b < 4; ++b) {
            int nb = c * 4 + b;
            int col = nb * 16 + m;
            float ev = e2[col];
            f32x4 acc[4];
            #pragma unroll
            for (int mt = 0; mt < 4; ++mt) acc[mt] = (f32x4){0.f, 0.f, 0.f, 0.f};
            #pragma unroll
            for (int t = 0; t < 4; ++t) {
                U4S8 bh;
                bh.u = buf[(b * 4 + t) * 64 + l];
                #pragma unroll
                for (int mt = 0; mt < 4; ++mt)
                    acc[mt] = __builtin_amdgcn_mfma_f32_16x16x32_bf16(ah[mt][t], bh.s, acc[mt], 0, 0, 0);
            }
            // top-3 update, index packed in low 10 mantissa bits (5 VALU/value)
            #pragma unroll
            for (int mt = 0; mt < 4; ++mt)
                #pragma unroll
                for (int r = 0; r < 4; ++r) {
                    int k = mt * 4 + r;
                    float s = fmaf(-2.0f, acc[mt][r], ev);
                    float sq = __uint_as_float((__float_as_uint(s) & 0xFFFFFC00u) | (unsigned)col);
                    float om2 = m2q[k];
                    m3[k]  = __builtin_amdgcn_fmed3f(sq, om2, m3[k]);
                    m2q[k] = __builtin_amdgcn_fmed3f(sq, m1q[k], om2);
                    m1q[k] = fminf(m1q[k], sq);
                }
        }
        __syncthreads();
    }

    // ---------- merge top-3 across the 16 col-partition lanes ----------
    #pragma unroll
    for (int k = 0; k < 16; ++k) {
        float a1 = m1q[k], a2 = m2q[k], a3 = m3[k];
        #pragma unroll
        for (int off = 1; off < 16; off <<= 1) {
            float b1 = __shfl_xor(a1, off, 64);
            float b2 = __shfl_xor(a2, off, 64);
            float b3 = __shfl_xor(a3, off, 64);
            float hi  = fmaxf(a1, b1);
            float lo2 = fminf(a2, b2);
            float n1 = fminf(a1, b1);
            float n2 = fminf(hi, lo2);
            float n3 = fminf(fminf(fmaxf(hi, lo2), fmaxf(a2, b2)), fminf(a3, b3));
            a1 = n1; a2 = n2; a3 = n3;
        }
        m1q[k] = a1; m2q[k] = a2; m3[k] = a3;
    }

    // ---------- idx write, hist, refine/recheck lists ----------
    int* idxs = (int*)&Bs[0][0];        // 256 ints
    int* hist = idxs + 256;             // 1024 ints
    float* wred = (float*)(hist + KCODE);
    for (int i = tid; i < KCODE; i += 256) hist[i] = 0;
    __syncthreads();
    if (m == 0) {
        #pragma unroll
        for (int mt = 0; mt < 4; ++mt)
            #pragma unroll
            for (int r = 0; r < 4; ++r) {
                int k = mt * 4 + r;
                int row_loc = w * 64 + mt * 16 + q * 4 + r;
                int row = row0 + row_loc;
                int i1 = (int)(__float_as_uint(m1q[k]) & 1023u);
                idx[row] = i1;
                idxs[row_loc] = i1;
                atomicAdd(&hist[i1], 1);
                if (m3[k] - m1q[k] <= BANDTRI) {
                    int pos = atomicAdd(rf_cnt, 1);
                    rf_rows[pos] = row;
                } else if (m2q[k] - m1q[k] <= BANDPAIR) {
                    int i2 = (int)(__float_as_uint(m2q[k]) & 1023u);
                    int pos = atomicAdd(rc_cnt, 1);
                    rc_rows[pos] = row;
                    rc_pair[pos] = (i1 << 10) | i2;
                }
            }
    }
    __syncthreads();
    for (int i = tid; i < KCODE; i += 256) {
        int h = hist[i];
        if (h) atomicAdd(&counts[i], h);
    }

    // ---------- fused quantize + commitment-loss partial ----------
    float lacc = 0.f;
    int li = l & 31, half = l >> 5;
    for (int jj = 0; jj < 32; ++jj) {
        int row_loc = w * 64 + jj * 2 + half;
        int k = idxs[row_loc];
        size_t grow = (size_t)(row0 + row_loc);
        float4 xv = ((const float4*)x)[grow * 32 + li];
        float4 ev = ((const float4*)ET)[(size_t)k * 32 + li];
        float t0 = ev.x - xv.x, t1 = ev.y - xv.y, t2 = ev.z - xv.z, t3 = ev.w - xv.w;
        float4 o; o.x = xv.x + t0; o.y = xv.y + t1; o.z = xv.z + t2; o.w = xv.w + t3;
        ((float4*)(out + OUT_QST))[grow * 32 + li] = o;
        lacc += t0 * t0 + t1 * t1 + t2 * t2 + t3 * t3;
    }
    #pragma unroll
    for (int off = 32; off > 0; off >>= 1) lacc += __shfl_down(lacc, off);
    if (l == 0) wred[w] = lacc;
    __syncthreads();
    if (tid == 0) partials[blockIdx.x] = wred[0] + wred[1] + wred[2] + wred[3];
}

// ============================================================
// Exact fp64 top-2 recheck; fixes idx/counts/q_st/loss if flipped.
__global__ void vq_recheck(const float* __restrict__ x, const float* __restrict__ ET,
                           const int* __restrict__ rc_rows, const int* __restrict__ rc_pair,
                           const int* __restrict__ rc_cnt, int* __restrict__ idx,
                           int* __restrict__ counts, float* __restrict__ out,
                           double* __restrict__ lossadj) {
    int w = threadIdx.x >> 6, l = threadIdx.x & 63;
    int gw = blockIdx.x * 4 + w;
    int cnt = *rc_cnt;
    for (int e = gw; e < cnt; e += 256 * 4) {
        int n = rc_rows[e];
        int pk = rc_pair[e];
        int i1 = pk >> 10, i2 = pk & 1023;
        float x0 = x[(size_t)n * DIMD + 2 * l];
        float x1 = x[(size_t)n * DIMD + 2 * l + 1];
        double da = 0.0, db = 0.0;
        {
            double d0 = (double)x0 - (double)ET[(size_t)i1 * DIMD + 2 * l];
            double d1 = (double)x1 - (double)ET[(size_t)i1 * DIMD + 2 * l + 1];
            da = d0 * d0 + d1 * d1;
            double e0 = (double)x0 - (double)ET[(size_t)i2 * DIMD + 2 * l];
            double e1 = (double)x1 - (double)ET[(size_t)i2 * DIMD + 2 * l + 1];
            db = e0 * e0 + e1 * e1;
        }
        #pragma unroll
        for (int off = 32; off > 0; off >>= 1) {
            da += __shfl_down(da, off);
            db += __shfl_down(db, off);
        }
        da = __shfl(da, 0, 64);
        db = __shfl(db, 0, 64);
        int win = (da < db) ? i1 : ((db < da) ? i2 : min(i1, i2));
        if (win != i1) {   // idx[n] == i1 by construction
            if (l == 0) {
                idx[n] = win;
                atomicSub(&counts[i1], 1);
                atomicAdd(&counts[win], 1);
                atomicAdd(lossadj, db - da);
            }
            float e0 = ET[(size_t)win * DIMD + 2 * l];
            float e1 = ET[(size_t)win * DIMD + 2 * l + 1];
            out[OUT_QST + (size_t)n * DIMD + 2 * l]     = x0 + (e0 - x0);
            out[OUT_QST + (size_t)n * DIMD + 2 * l + 1] = x1 + (e1 - x1);
        }
    }
}

// Full fp64 refine (4 rows share one E sweep); fixes everything if changed.
__global__ void vq_refine(const float* __restrict__ x, const float* __restrict__ E,
                          const float* __restrict__ ET, const int* __restrict__ rf_rows,
                          const int* __restrict__ rf_cnt, int* __restrict__ idx,
                          int* __restrict__ counts, float* __restrict__ out,
                          double* __restrict__ lossadj) {
    __shared__ float xs[4][DIMD];
    __shared__ double rm[256];
    __shared__ int ri[256];
    __shared__ double dred[DIMD];
    int tid = threadIdx.x;
    int cnt = *rf_cnt;
    for (int base = blockIdx.x * 4; base < cnt; base += gridDim.x * 4) {
        int nr = min(4, cnt - base);
        __syncthreads();
        for (int i = tid; i < nr * DIMD; i += 256)
            xs[i >> 7][i & 127] = x[(size_t)rf_rows[base + (i >> 7)] * DIMD + (i & 127)];
        __syncthreads();
        double best[4]; int bk[4];
        #pragma unroll
        for (int rr = 0; rr < 4; ++rr) { best[rr] = DBL_MAX; bk[rr] = 0; }
        for (int kk = 0; kk < 4; ++kk) {
            int k = tid + kk * 256;
            double a0 = 0, a1 = 0, a2 = 0, a3 = 0;
            for (int d = 0; d < DIMD; ++d) {
                double ev = (double)E[(size_t)d * KCODE + k];
                double t0 = (double)xs[0][d] - ev; a0 = fma(t0, t0, a0);
                double t1 = (double)xs[1][d] - ev; a1 = fma(t1, t1, a1);
                double t2 = (double)xs[2][d] - ev; a2 = fma(t2, t2, a2);
                double t3 = (double)xs[3][d] - ev; a3 = fma(t3, t3, a3);
            }
            double av[4] = {a0, a1, a2, a3};
            #pragma unroll
            for (int rr = 0; rr < 4; ++rr)
                if (av[rr] < best[rr] || (av[rr] == best[rr] && k < bk[rr])) {
                    best[rr] = av[rr]; bk[rr] = k;
                }
        }
        for (int rr = 0; rr < nr; ++rr) {
            __syncthreads();
            rm[tid] = best[rr]; ri[tid] = bk[rr];
            __syncthreads();
            for (int off = 128; off > 0; off >>= 1) {
                if (tid < off) {
                    double o = rm[tid + off]; int oi = ri[tid + off];
                    if (o < rm[tid] || (o == rm[tid] && oi < ri[tid])) {
                        rm[tid] = o; ri[tid] = oi;
                    }
                }
                __syncthreads();
            }
            int n = rf_rows[base + rr];
            int newk = ri[0], oldk = idx[n];
            if (newk != oldk) {
                // exact distance of oldk (for loss delta)
                if (tid < DIMD) {
                    double t = (double)xs[rr][tid] - (double)ET[(size_t)oldk * DIMD + tid];
                    dred[tid] = t * t;
                }
                __syncthreads();
                for (int off = 64; off > 0; off >>= 1) {
                    if (tid < off) dred[tid] += dred[tid + off];
                    __syncthreads();
                }
                if (tid == 0) {
                    idx[n] = newk;
                    atomicSub(&counts[oldk], 1);
                    atomicAdd(&counts[newk], 1);
                    atomicAdd(lossadj, rm[0] - dred[0]);
                }
                if (tid < DIMD) {
                    float xv = xs[rr][tid];
                    float e = ET[(size_t)newk * DIMD + tid];
                    out[OUT_QST + (size_t)n * DIMD + tid] = xv + (e - xv);
                }
            }
        }
    }
}

// ============================================================
__global__ void vq_scan(const int* __restrict__ counts, int* __restrict__ offsets,
                        int* __restrict__ cursor) {
    __shared__ int s[KCODE];
    int t = threadIdx.x;
    int c = counts[t];
    s[t] = c;
    __syncthreads();
    for (int off = 1; off < KCODE; off <<= 1) {
        int v = (t >= off) ? s[t - off] : 0;
        __syncthreads();
        s[t] += v;
        __syncthreads();
    }
    int excl = s[t] - c;
    offsets[t] = excl;
    cursor[t] = excl;
}

__global__ void vq_fill(const int* __restrict__ idx, int* __restrict__ cursor,
                        int* __restrict__ rowlist) {
    __shared__ int hcnt[KCODE];
    __shared__ int hbase[KCODE];
    int tid = threadIdx.x;
    for (int i = tid; i < KCODE; i += 256) hcnt[i] = 0;
    __syncthreads();
    int n = blockIdx.x * 256 + tid;
    int k = idx[n];
    int lrank = atomicAdd(&hcnt[k], 1);
    __syncthreads();
    for (int i = tid; i < KCODE; i += 256) {
        int h = hcnt[i];
        if (h) hbase[i] = atomicAdd(&cursor[i], h);
    }
    __syncthreads();
    rowlist[hbase[k] + lrank] = n;
}

__global__ void vq_chunksum(const float* __restrict__ x,
                            const int* __restrict__ rowlist,
                            const int* __restrict__ idx,
                            float* __restrict__ sums) {
    __shared__ int rl[128];
    __shared__ int kk[128];
    int tid = threadIdx.x;   // 128 threads, tid == d
    int base = blockIdx.x * 128;
    int r = rowlist[base + tid];
    rl[tid] = r;
    kk[tid] = idx[r];
    __syncthreads();
    float s = 0.f;
    int kprev = kk[0];
    #pragma unroll 4
    for (int j = 0; j < 128; ++j) {
        int kj = kk[j];
        if (kj != kprev) {
            atomicAdd(&sums[(size_t)kprev * DIMD + tid], s);
            s = 0.f;
            kprev = kj;
        }
        s += x[(size_t)rl[j] * DIMD + tid];
    }
    atomicAdd(&sums[(size_t)kprev * DIMD + tid], s);
}

__global__ void vq_finalize_emb(const int* __restrict__ counts,
                                const float* __restrict__ sums,
                                const float* __restrict__ emc,
                                const float* __restrict__ es,
                                float* __restrict__ out) {
    int gid = blockIdx.x * 256 + threadIdx.x;   // 131072
    int k = gid & (KCODE - 1), d = gid >> 10;
    float cnt = (float)counts[k];
    float ecn = fmaf(0.85f, cnt, 0.15f * emc[k]);
    float esn = fmaf(0.85f, sums[(size_t)k * DIMD + d], 0.15f * es[(size_t)d * KCODE + k]);
    out[OUT_ES + (size_t)d * KCODE + k] = esn;
    out[OUT_EMB + (size_t)d * KCODE + k] = esn / fmaxf(ecn, 1e-5f);
    if (d == 0) out[OUT_CNT + k] = ecn;
}

__global__ void vq_finalize_loss(const float* __restrict__ partials,
                                 const double* __restrict__ lossadj,
                                 float* __restrict__ out) {
    float s = 0.f;
    for (int i = threadIdx.x; i < 512; i += 256) s += partials[i];
    #pragma unroll
    for (int off = 32; off > 0; off >>= 1) s += __shfl_down(s, off);
    __shared__ float wsum[4];
    int wave = threadIdx.x >> 6;
    if ((threadIdx.x & 63) == 0) wsum[wave] = s;
    __syncthreads();
    if (threadIdx.x == 0) {
        double tot = (double)(wsum[0] + wsum[1] + wsum[2] + wsum[3]) + *lossadj;
        out[OUT_LOSS] = (float)(tot / ((double)NROWS * (double)DIMD));  // BETA = 1
    }
}

// ============================================================
extern "C" void kernel_launch(void* const* d_in, const int* in_sizes, int n_in,
                              void* d_out, int out_size, void* d_ws, size_t ws_size,
                              hipStream_t stream) {
    const float* x   = (const float*)d_in[0];
    const float* E   = (const float*)d_in[1];
    const float* emc = (const float*)d_in[2];
    const float* es  = (const float*)d_in[3];
    float* out = (float*)d_out;
    char* ws = (char*)d_ws;

    int*    rf_cnt   = (int*)(ws + WS_RF_CNT);
    int*    rc_cnt   = (int*)(ws + WS_RC_CNT);
    double* lossadj  = (double*)(ws + WS_LOSSADJ);
    int*    counts   = (int*)(ws + WS_COUNTS);
    float*  sums     = (float*)(ws + WS_SUMS);
    int*    offsets  = (int*)(ws + WS_OFFSETS);
    int*    cursor   = (int*)(ws + WS_CURSOR);
    float*  e2       = (float*)(ws + WS_E2);
    float*  ET       = (float*)(ws + WS_ET);
    uint4*  Bhi      = (uint4*)(ws + WS_BHI);
    int*    idx      = (int*)(ws + WS_IDX);
    int*    rowlist  = (int*)(ws + WS_ROWLIST);
    int*    rf_rows  = (int*)(ws + WS_RF_ROWS);
    int*    rc_rows  = (int*)(ws + WS_RC_ROWS);
    int*    rc_pair  = (int*)(ws + WS_RC_PAIR);
    float*  partials = (float*)(ws + WS_PARTIALS);

    hipMemsetAsync(ws, 0, WS_ZERO_BYTES, stream);

    vq_prep<<<64, 256, 0, stream>>>(E, e2, Bhi);
    vq_transpose<<<dim3(KCODE / 32, DIMD / 32), dim3(32, 8), 0, stream>>>(E, ET);
    vq_argmin<<<NROWS / 256, 256, 0, stream>>>(x, Bhi, e2, ET, idx, counts,
                                               rc_rows, rc_pair, rc_cnt,
                                               rf_rows, rf_cnt, out, partials);
    vq_recheck<<<256, 256, 0, stream>>>(x, ET, rc_rows, rc_pair, rc_cnt, idx,
                                        counts, out, lossadj);
    vq_refine<<<128, 256, 0, stream>>>(x, E, ET, rf_rows, rf_cnt, idx, counts,
                                       out, lossadj);
    vq_scan<<<1, KCODE, 0, stream>>>(counts, offsets, cursor);
    vq_fill<<<NROWS / 256, 256, 0, stream>>>(idx, cursor, rowlist);
    vq_chunksum<<<NROWS / 128, 128, 0, stream>>>(x, rowlist, idx, sums);
    vq_finalize_emb<<<(DIMD * KCODE) / 256, 256, 0, stream>>>(counts, sums, emc, es, out);
    vq_finalize_loss<<<1, 256, 0, stream>>>(partials, lossadj, out);
}

// Round 6
// 551.538 us; speedup vs baseline: 1.1358x; 1.1358x over previous
//
#include <hip/hip_runtime.h>
#include <cfloat>
#include <cstdint>

// Problem constants
#define NROWS 131072
#define DIMD  128
#define KCODE 1024
// 1-pass bf16 score error: sigma ~0.03 per code; bands are ~7-8 sigma on the
// error DIFFERENCE of two codes. Outside tri-band the argmin is provably in
// {i1,i2}; inside -> exact full sweep.
#define BANDPAIR 0.28f
#define BANDTRI  0.32f

typedef __attribute__((ext_vector_type(8))) short short8;  // 8 bf16 = 4 VGPRs
typedef __attribute__((ext_vector_type(4))) float f32x4;

union U4S8 { uint4 u; short8 s; };

// ---- workspace layout (bytes) ----
#define WS_RF_CNT    0          // int   (full-refine count)
#define WS_RC_CNT    4          // int   (recheck count)
#define WS_PAD       8          // 8B pad
#define WS_COUNTS    16         // int[1024]
#define WS_SUMS      4608       // float[K*D] = 512 KB ([k][d])
#define WS_ZERO_BYTES 528896    // memset [0, WS_ZERO_BYTES)
#define WS_OFFSETS   528896     // int[1024]
#define WS_CURSOR    532992     // int[1024]
#define WS_E2        537088     // float[1024]
#define WS_ET        541184     // float[K*D] (ET[k][d])
#define WS_BHI       1065472    // uint4[16384] = 256 KB (B hi fragments)
#define WS_IDX       1327616    // int[N]
#define WS_ROWLIST   1851904    // int[N]
#define WS_RF_ROWS   2376192    // int[N]
#define WS_RC_ROWS   2900480    // int[N]
#define WS_RC_PAIR   3424768    // int[N]  ((i1<<10)|i2)
#define WS_PARTIALS  3949056    // float[512] per-block loss partials
// end: 3951104

// ---- output offsets (in floats), reference return order ----
#define OUT_QST  ((size_t)0)
#define OUT_EMB  ((size_t)NROWS * DIMD)
#define OUT_CNT  (OUT_EMB + (size_t)DIMD * KCODE)
#define OUT_ES   (OUT_CNT + KCODE)
#define OUT_LOSS (OUT_ES + (size_t)DIMD * KCODE)

// bf16 round-to-nearest-even of a float, as uint16 payload
__device__ __forceinline__ unsigned bf16rne(float f) {
    union { float f; unsigned u; } c; c.f = f;
    return (c.u + 0x7fffu + ((c.u >> 16) & 1u)) >> 16;
}

// ============================================================
// Fused prep: B hi-fragments in MFMA order + e2[k] = sum_d E[d][k]^2.
__global__ void vq_prep(const float* __restrict__ E, float* __restrict__ e2,
                        uint4* __restrict__ Bhi) {
    int gid = blockIdx.x * 256 + threadIdx.x;   // 0..16383 == fi
    int l = gid & 63;
    int t = (gid >> 6) & 3;
    int NB = gid >> 8;
    int n = NB * 16 + (l & 15);
    int k0 = t * 32 + (l >> 4) * 8;
    unsigned hu[8];
    #pragma unroll
    for (int j = 0; j < 8; ++j)
        hu[j] = bf16rne(E[(size_t)(k0 + j) * KCODE + n]);
    Bhi[gid] = make_uint4(hu[0] | (hu[1] << 16), hu[2] | (hu[3] << 16),
                          hu[4] | (hu[5] << 16), hu[6] | (hu[7] << 16));
    if (gid < KCODE) {
        float s = 0.f;
        for (int d = 0; d < DIMD; ++d) {
            float v = E[(size_t)d * KCODE + gid];
            s = fmaf(v, v, s);
        }
        e2[gid] = s;
    }
}

// ET[k][d] = E[d][k]  (LDS-tiled transpose)
__global__ void vq_transpose(const float* __restrict__ E, float* __restrict__ ET) {
    __shared__ float tile[32][33];
    int kb = blockIdx.x * 32, db = blockIdx.y * 32;
    int tx = threadIdx.x, ty = threadIdx.y;  // 32 x 8
    #pragma unroll
    for (int j = 0; j < 32; j += 8)
        tile[ty + j][tx] = E[(size_t)(db + ty + j) * KCODE + kb + tx];
    __syncthreads();
    #pragma unroll
    for (int j = 0; j < 32; j += 8)
        ET[(size_t)(kb + ty + j) * DIMD + db + tx] = tile[tx][ty + j];
}

// ============================================================
__device__ __forceinline__ void async16(const uint4* g, uint4* l) {
    __builtin_amdgcn_global_load_lds(
        (const __attribute__((address_space(1))) void*)g,
        (__attribute__((address_space(3))) void*)l, 16, 0, 0);
}

// Main kernel: 1-pass bf16 MFMA scores s = e2[k] - 2 x.e_k, per-row top-3
// (col index packed in low 10 mantissa bits, med3 branchless). 256 rows/block,
// 4 waves x 64 rows. Fused epilogue: histogram (+ GLOBAL counts flush — R5
// dropped this and corrupted vq_fill's cursors -> OOB fault), recheck/refine
// lists, q_st gather-write (= ET[k], no x re-read), loss from m1 + ||x||^2.
// launch_bounds(256,2): R3-proven VGPR budget — K-loop state ~145 regs must
// NOT spill (R4's (256,3) gave VGPR=84 + ~70 MB scratch traffic, 2x slower).
__global__ __launch_bounds__(256, 2) void vq_argmin(
        const float* __restrict__ x, const uint4* __restrict__ Bhi,
        const float* __restrict__ e2, const float* __restrict__ ET,
        int* __restrict__ idx, int* __restrict__ counts,
        int* __restrict__ rc_rows, int* __restrict__ rc_pair, int* __restrict__ rc_cnt,
        int* __restrict__ rf_rows, int* __restrict__ rf_cnt,
        float* __restrict__ out, float* __restrict__ partials) {

    __shared__ uint4 Bs[2][1024];   // 2 x 16 KB (prologue: 4x8KB wave scratch)
    __shared__ float x2s[256];      // per-row ||x||^2

    const int tid = threadIdx.x;
    const int w = tid >> 6, l = tid & 63;
    const int m = l & 15, q = l >> 4;
    const int row0 = blockIdx.x * 256;
    const int rw = row0 + w * 64;

    // ---------- A-phase: build hi A-fragments + per-row x2 ----------
    short8 ah[4][4];                                 // [m-tile][k-tile]
    float4* sc4 = ((float4*)&Bs[0][0]) + w * 512;    // 8 KB scratch per wave

    #pragma unroll
    for (int mt = 0; mt < 4; ++mt) {
        int rm = rw + mt * 16;
        #pragma unroll
        for (int i = 0; i < 8; ++i) {
            int f = i * 64 + l, r = f >> 5, g = f & 31;
            float4 v = ((const float4*)x)[(size_t)(rm + r) * 32 + g];
            sc4[r * 32 + (g ^ ((r & 7) << 2))] = v;
        }
        __builtin_amdgcn_s_waitcnt(0);
        int sw = (m & 7) << 2;
        float x2 = 0.f;
        #pragma unroll
        for (int t = 0; t < 4; ++t) {
            int g0 = t * 8 + q * 2;
            float4 va = sc4[m * 32 + (g0 ^ sw)];
            float4 vb = sc4[m * 32 + ((g0 + 1) ^ sw)];
            float f8[8] = {va.x, va.y, va.z, va.w, vb.x, vb.y, vb.z, vb.w};
            unsigned hu[8];
            #pragma unroll
            for (int j = 0; j < 8; ++j) {
                x2 = fmaf(f8[j], f8[j], x2);
                hu[j] = bf16rne(f8[j]);
            }
            U4S8 ch;
            ch.u = make_uint4(hu[0] | (hu[1] << 16), hu[2] | (hu[3] << 16),
                              hu[4] | (hu[5] << 16), hu[6] | (hu[7] << 16));
            ah[mt][t] = ch.s;
        }
        // reduce x2 across the 4 q-lanes sharing row m
        x2 += __shfl_xor(x2, 16, 64);
        x2 += __shfl_xor(x2, 32, 64);
        if (l < 16) x2s[w * 64 + mt * 16 + m] = x2;
    }

    float m1q[16], m2q[16], m3[16];   // slot = mt*4 + r
    #pragma unroll
    for (int k = 0; k < 16; ++k) { m1q[k] = 1e30f; m2q[k] = 1e30f; m3[k] = 1e30f; }

    __syncthreads();   // scratch reads done before staging overwrites

    // stage chunk 0 (16 KB, wave-partitioned)
    {
        const uint4* src = Bhi + w * 256 + l;
        uint4* dst = &Bs[0][0] + w * 256;
        #pragma unroll
        for (int j = 0; j < 4; ++j) async16(src + j * 64, dst + j * 64 + l);
    }
    __syncthreads();

    for (int c = 0; c < 16; ++c) {
        if (c < 15) {
            const uint4* src = Bhi + (c + 1) * 1024 + w * 256 + l;
            uint4* dst = &Bs[(c + 1) & 1][0] + w * 256;
            #pragma unroll
            for (int j = 0; j < 4; ++j) async16(src + j * 64, dst + j * 64 + l);
        }
        const uint4* buf = &Bs[c & 1][0];
        #pragma unroll
        for (int b = 0; b < 4; ++b) {
            int nb = c * 4 + b;
            int col = nb * 16 + m;
            float ev = e2[col];
            f32x4 acc[4];
            #pragma unroll
            for (int mt = 0; mt < 4; ++mt) acc[mt] = (f32x4){0.f, 0.f, 0.f, 0.f};
            #pragma unroll
            for (int t = 0; t < 4; ++t) {
                U4S8 bh;
                bh.u = buf[(b * 4 + t) * 64 + l];
                #pragma unroll
                for (int mt = 0; mt < 4; ++mt)
                    acc[mt] = __builtin_amdgcn_mfma_f32_16x16x32_bf16(ah[mt][t], bh.s, acc[mt], 0, 0, 0);
            }
            #pragma unroll
            for (int mt = 0; mt < 4; ++mt)
                #pragma unroll
                for (int r = 0; r < 4; ++r) {
                    int k = mt * 4 + r;
                    float s = fmaf(-2.0f, acc[mt][r], ev);
                    float sq = __uint_as_float((__float_as_uint(s) & 0xFFFFFC00u) | (unsigned)col);
                    float om2 = m2q[k];
                    m3[k]  = __builtin_amdgcn_fmed3f(sq, om2, m3[k]);
                    m2q[k] = __builtin_amdgcn_fmed3f(sq, m1q[k], om2);
                    m1q[k] = fminf(m1q[k], sq);
                }
        }
        __syncthreads();
    }

    // ---------- merge top-3 across the 16 col-partition lanes ----------
    #pragma unroll
    for (int k = 0; k < 16; ++k) {
        float a1 = m1q[k], a2 = m2q[k], a3 = m3[k];
        #pragma unroll
        for (int off = 1; off < 16; off <<= 1) {
            float b1 = __shfl_xor(a1, off, 64);
            float b2 = __shfl_xor(a2, off, 64);
            float b3 = __shfl_xor(a3, off, 64);
            float hi  = fmaxf(a1, b1);
            float lo2 = fminf(a2, b2);
            float n1 = fminf(a1, b1);
            float n2 = fminf(hi, lo2);
            float n3 = fminf(fminf(fmaxf(hi, lo2), fmaxf(a2, b2)), fminf(a3, b3));
            a1 = n1; a2 = n2; a3 = n3;
        }
        m1q[k] = a1; m2q[k] = a2; m3[k] = a3;
    }

    // ---------- idx write, hist, refine/recheck lists, loss partial ----------
    int* idxs = (int*)&Bs[0][0];        // 256 ints
    int* hist = idxs + 256;             // 1024 ints
    float* wred = (float*)(hist + KCODE);
    for (int i = tid; i < KCODE; i += 256) hist[i] = 0;
    __syncthreads();
    float lacc = 0.f;
    if (m == 0) {
        #pragma unroll
        for (int mt = 0; mt < 4; ++mt)
            #pragma unroll
            for (int r = 0; r < 4; ++r) {
                int k = mt * 4 + r;
                int row_loc = w * 64 + mt * 16 + q * 4 + r;
                int row = row0 + row_loc;
                unsigned u1 = __float_as_uint(m1q[k]);
                int i1 = (int)(u1 & 1023u);
                float s1 = __uint_as_float(u1 & 0xFFFFFC00u);
                idx[row] = i1;
                idxs[row_loc] = i1;
                atomicAdd(&hist[i1], 1);
                lacc += s1 + x2s[row_loc];   // ~ ||x - e_i1||^2
                if (m3[k] - m1q[k] <= BANDTRI) {
                    int pos = atomicAdd(rf_cnt, 1);
                    rf_rows[pos] = row;
                } else if (m2q[k] - m1q[k] <= BANDPAIR) {
                    int i2 = (int)(__float_as_uint(m2q[k]) & 1023u);
                    int pos = atomicAdd(rc_cnt, 1);
                    rc_rows[pos] = row;
                    rc_pair[pos] = (i1 << 10) | i2;
                }
            }
    }
    #pragma unroll
    for (int off = 32; off > 0; off >>= 1) lacc += __shfl_down(lacc, off);
    if (l == 0) wred[w] = lacc;
    __syncthreads();
    if (tid == 0) partials[blockIdx.x] = wred[0] + wred[1] + wred[2] + wred[3];

    // flush block-local histogram to global counts (REQUIRED by scan/fill —
    // dropping this in R5 caused negative cursors -> OOB writes -> SIGABRT)
    for (int i = tid; i < KCODE; i += 256) {
        int h = hist[i];
        if (h) atomicAdd(&counts[i], h);
    }

    // ---------- q_st gather-write: out row = ET[k] (no x re-read) ----------
    int li = l & 31, half = l >> 5;
    for (int jj = 0; jj < 32; ++jj) {
        int row_loc = w * 64 + jj * 2 + half;
        int k = idxs[row_loc];
        float4 ev4 = ((const float4*)ET)[(size_t)k * 32 + li];
        ((float4*)(out + OUT_QST))[((size_t)(row0 + row_loc)) * 32 + li] = ev4;
    }
}

// ============================================================
// Exact fp64 top-2 recheck; fixes idx/counts/q_st if flipped.
__global__ void vq_recheck(const float* __restrict__ x, const float* __restrict__ ET,
                           const int* __restrict__ rc_rows, const int* __restrict__ rc_pair,
                           const int* __restrict__ rc_cnt, int* __restrict__ idx,
                           int* __restrict__ counts, float* __restrict__ out) {
    int w = threadIdx.x >> 6, l = threadIdx.x & 63;
    int gw = blockIdx.x * 4 + w;
    int nw = gridDim.x * 4;
    int cnt = *rc_cnt;
    for (int e = gw; e < cnt; e += nw) {
        int n = rc_rows[e];
        int pk = rc_pair[e];
        int i1 = pk >> 10, i2 = pk & 1023;
        float x0 = x[(size_t)n * DIMD + 2 * l];
        float x1 = x[(size_t)n * DIMD + 2 * l + 1];
        double d0 = (double)x0 - (double)ET[(size_t)i1 * DIMD + 2 * l];
        double d1 = (double)x1 - (double)ET[(size_t)i1 * DIMD + 2 * l + 1];
        double da = d0 * d0 + d1 * d1;
        double e0 = (double)x0 - (double)ET[(size_t)i2 * DIMD + 2 * l];
        double e1 = (double)x1 - (double)ET[(size_t)i2 * DIMD + 2 * l + 1];
        double db = e0 * e0 + e1 * e1;
        #pragma unroll
        for (int off = 32; off > 0; off >>= 1) {
            da += __shfl_down(da, off);
            db += __shfl_down(db, off);
        }
        da = __shfl(da, 0, 64);
        db = __shfl(db, 0, 64);
        int win = (da < db) ? i1 : ((db < da) ? i2 : min(i1, i2));
        if (win != i1) {   // idx[n] == i1 by construction
            if (l == 0) {
                idx[n] = win;
                atomicSub(&counts[i1], 1);
                atomicAdd(&counts[win], 1);
            }
            out[OUT_QST + (size_t)n * DIMD + 2 * l]     = ET[(size_t)win * DIMD + 2 * l];
            out[OUT_QST + (size_t)n * DIMD + 2 * l + 1] = ET[(size_t)win * DIMD + 2 * l + 1];
        }
    }
}

// Full fp64 refine: 8 rows share one E sweep; fixes idx/counts/q_st.
__global__ void vq_refine(const float* __restrict__ x, const float* __restrict__ E,
                          const float* __restrict__ ET, const int* __restrict__ rf_rows,
                          const int* __restrict__ rf_cnt, int* __restrict__ idx,
                          int* __restrict__ counts, float* __restrict__ out) {
    __shared__ float xs[8][DIMD];
    __shared__ double rm[256];
    __shared__ int ri[256];
    int tid = threadIdx.x;
    int cnt = *rf_cnt;
    for (int base = blockIdx.x * 8; base < cnt; base += gridDim.x * 8) {
        int nr = min(8, cnt - base);
        __syncthreads();
        for (int i = tid; i < 8 * DIMD; i += 256) {
            int rr = i >> 7;
            xs[rr][i & 127] = (rr < nr) ? x[(size_t)rf_rows[base + rr] * DIMD + (i & 127)] : 0.f;
        }
        __syncthreads();
        double best[8]; int bk[8];
        #pragma unroll
        for (int rr = 0; rr < 8; ++rr) { best[rr] = DBL_MAX; bk[rr] = 0; }
        for (int kk = 0; kk < 4; ++kk) {
            int k = tid + kk * 256;   // ascending k per thread -> first-idx ties
            double a[8];
            #pragma unroll
            for (int rr = 0; rr < 8; ++rr) a[rr] = 0.0;
            for (int d = 0; d < DIMD; ++d) {
                double evv = (double)E[(size_t)d * KCODE + k];
                #pragma unroll
                for (int rr = 0; rr < 8; ++rr) {
                    double t = (double)xs[rr][d] - evv;
                    a[rr] = fma(t, t, a[rr]);
                }
            }
            #pragma unroll
            for (int rr = 0; rr < 8; ++rr)
                if (a[rr] < best[rr]) { best[rr] = a[rr]; bk[rr] = k; }
        }
        for (int rr = 0; rr < nr; ++rr) {
            __syncthreads();
            rm[tid] = best[rr]; ri[tid] = bk[rr];
            __syncthreads();
            for (int off = 128; off > 0; off >>= 1) {
                if (tid < off) {
                    double o = rm[tid + off]; int oi = ri[tid + off];
                    if (o < rm[tid] || (o == rm[tid] && oi < ri[tid])) {
                        rm[tid] = o; ri[tid] = oi;
                    }
                }
                __syncthreads();
            }
            int n = rf_rows[base + rr];
            int newk = ri[0], oldk = idx[n];
            if (newk != oldk) {
                if (tid == 0) {
                    idx[n] = newk;
                    atomicSub(&counts[oldk], 1);
                    atomicAdd(&counts[newk], 1);
                }
                if (tid < DIMD)
                    out[OUT_QST + (size_t)n * DIMD + tid] = ET[(size_t)newk * DIMD + tid];
            }
        }
    }
}

// ============================================================
__global__ void vq_scan(const int* __restrict__ counts, int* __restrict__ offsets,
                        int* __restrict__ cursor) {
    __shared__ int s[KCODE];
    int t = threadIdx.x;
    int c = counts[t];
    s[t] = c;
    __syncthreads();
    for (int off = 1; off < KCODE; off <<= 1) {
        int v = (t >= off) ? s[t - off] : 0;
        __syncthreads();
        s[t] += v;
        __syncthreads();
    }
    int excl = s[t] - c;
    offsets[t] = excl;
    cursor[t] = excl;
}

__global__ void vq_fill(const int* __restrict__ idx, int* __restrict__ cursor,
                        int* __restrict__ rowlist) {
    __shared__ int hcnt[KCODE];
    __shared__ int hbase[KCODE];
    int tid = threadIdx.x;
    for (int i = tid; i < KCODE; i += 256) hcnt[i] = 0;
    __syncthreads();
    int n = blockIdx.x * 256 + tid;
    int k = idx[n];
    int lrank = atomicAdd(&hcnt[k], 1);
    __syncthreads();
    for (int i = tid; i < KCODE; i += 256) {
        int h = hcnt[i];
        if (h) hbase[i] = atomicAdd(&cursor[i], h);
    }
    __syncthreads();
    rowlist[hbase[k] + lrank] = n;
}

__global__ void vq_chunksum(const float* __restrict__ x,
                            const int* __restrict__ rowlist,
                            const int* __restrict__ idx,
                            float* __restrict__ sums) {
    __shared__ int rl[128];
    __shared__ int kk[128];
    int tid = threadIdx.x;   // 128 threads, tid == d
    int base = blockIdx.x * 128;
    int r = rowlist[base + tid];
    rl[tid] = r;
    kk[tid] = idx[r];
    __syncthreads();
    float s = 0.f;
    int kprev = kk[0];
    #pragma unroll 4
    for (int j = 0; j < 128; ++j) {
        int kj = kk[j];
        if (kj != kprev) {
            atomicAdd(&sums[(size_t)kprev * DIMD + tid], s);
            s = 0.f;
            kprev = kj;
        }
        s += x[(size_t)rl[j] * DIMD + tid];
    }
    atomicAdd(&sums[(size_t)kprev * DIMD + tid], s);
}

__global__ void vq_finalize_emb(const int* __restrict__ counts,
                                const float* __restrict__ sums,
                                const float* __restrict__ emc,
                                const float* __restrict__ es,
                                float* __restrict__ out) {
    int gid = blockIdx.x * 256 + threadIdx.x;   // 131072
    int k = gid & (KCODE - 1), d = gid >> 10;
    float cnt = (float)counts[k];
    float ecn = fmaf(0.85f, cnt, 0.15f * emc[k]);
    float esn = fmaf(0.85f, sums[(size_t)k * DIMD + d], 0.15f * es[(size_t)d * KCODE + k]);
    out[OUT_ES + (size_t)d * KCODE + k] = esn;
    out[OUT_EMB + (size_t)d * KCODE + k] = esn / fmaxf(ecn, 1e-5f);
    if (d == 0) out[OUT_CNT + k] = ecn;
}

__global__ void vq_finalize_loss(const float* __restrict__ partials,
                                 float* __restrict__ out) {
    float s = 0.f;
    for (int i = threadIdx.x; i < 512; i += 256) s += partials[i];
    #pragma unroll
    for (int off = 32; off > 0; off >>= 1) s += __shfl_down(s, off);
    __shared__ float wsum[4];
    int wave = threadIdx.x >> 6;
    if ((threadIdx.x & 63) == 0) wsum[wave] = s;
    __syncthreads();
    if (threadIdx.x == 0) {
        float tot = wsum[0] + wsum[1] + wsum[2] + wsum[3];
        out[OUT_LOSS] = tot / ((float)NROWS * (float)DIMD);  // BETA = 1
    }
}

// ============================================================
extern "C" void kernel_launch(void* const* d_in, const int* in_sizes, int n_in,
                              void* d_out, int out_size, void* d_ws, size_t ws_size,
                              hipStream_t stream) {
    const float* x   = (const float*)d_in[0];
    const float* E   = (const float*)d_in[1];
    const float* emc = (const float*)d_in[2];
    const float* es  = (const float*)d_in[3];
    float* out = (float*)d_out;
    char* ws = (char*)d_ws;

    int*    rf_cnt   = (int*)(ws + WS_RF_CNT);
    int*    rc_cnt   = (int*)(ws + WS_RC_CNT);
    int*    counts   = (int*)(ws + WS_COUNTS);
    float*  sums     = (float*)(ws + WS_SUMS);
    int*    offsets  = (int*)(ws + WS_OFFSETS);
    int*    cursor   = (int*)(ws + WS_CURSOR);
    float*  e2       = (float*)(ws + WS_E2);
    float*  ET       = (float*)(ws + WS_ET);
    uint4*  Bhi      = (uint4*)(ws + WS_BHI);
    int*    idx      = (int*)(ws + WS_IDX);
    int*    rowlist  = (int*)(ws + WS_ROWLIST);
    int*    rf_rows  = (int*)(ws + WS_RF_ROWS);
    int*    rc_rows  = (int*)(ws + WS_RC_ROWS);
    int*    rc_pair  = (int*)(ws + WS_RC_PAIR);
    float*  partials = (float*)(ws + WS_PARTIALS);

    hipMemsetAsync(ws, 0, WS_ZERO_BYTES, stream);

    vq_prep<<<64, 256, 0, stream>>>(E, e2, Bhi);
    vq_transpose<<<dim3(KCODE / 32, DIMD / 32), dim3(32, 8), 0, stream>>>(E, ET);
    vq_argmin<<<NROWS / 256, 256, 0, stream>>>(x, Bhi, e2, ET, idx, counts,
                                               rc_rows, rc_pair, rc_cnt,
                                               rf_rows, rf_cnt, out, partials);
    vq_recheck<<<512, 256, 0, stream>>>(x, ET, rc_rows, rc_pair, rc_cnt, idx,
                                        counts, out);
    vq_refine<<<256, 256, 0, stream>>>(x, E, ET, rf_rows, rf_cnt, idx, counts, out);
    vq_scan<<<1, KCODE, 0, stream>>>(counts, offsets, cursor);
    vq_fill<<<NROWS / 256, 256, 0, stream>>>(idx, cursor, rowlist);
    vq_chunksum<<<NROWS / 128, 128, 0, stream>>>(x, rowlist, idx, sums);
    vq_finalize_emb<<<(DIMD * KCODE) / 256, 256, 0, stream>>>(counts, sums, emc, es, out);
    vq_finalize_loss<<<1, 256, 0, stream>>>(partials, out);
}